// Round 7
// baseline (127.794 us; speedup 1.0000x reference)
//
#include <hip/hip_runtime.h>
#include <hip/hip_bf16.h>
#include <hip/hip_cooperative_groups.h>

namespace cg = cooperative_groups;

// out[q] = min(|{r : dist(q,r) <= thr}|, 100) / 100   (top-k unnecessary:
// any distance <= thr is among the 100 smallest unless count > 100, which clamps)
//
// Q=4096, R=16384, D=128. hit <=> dot(q,r) >= 0.5|q|^2 + (0.5|r|^2 - 0.5 thr^2)
// Single cooperative kernel: phase0 prep (bf16 cast, norms) -> grid.sync ->
// phase1 32x32x16-MFMA distance-count (depth-3 LDS ring, counted vmcnt) ->
// phase2 arrival-counter finalize. Zero inter-kernel launch gaps.

#define DIM   128
#define ROWB  256              // bytes per bf16 row
#define BM    512              // queries per block (4 waves x 128)
#define BN    32               // refs per round
#define NSEG  64               // segments along R (256 refs each)
#define NBLK  512              // 8 tileM x 64 seg = exactly 2 blocks/CU

typedef __attribute__((ext_vector_type(8)))  short short8;
typedef __attribute__((ext_vector_type(16))) float f32x16;

#define VMCNT(n) asm volatile("s_waitcnt vmcnt(" #n ")" ::: "memory")

__launch_bounds__(256, 2)
__global__ void fused_kernel(const float* __restrict__ qe, const float* __restrict__ re,
                             const float* __restrict__ thr_p,
                             __hip_bfloat16* __restrict__ qb, __hip_bfloat16* __restrict__ rb,
                             float* __restrict__ qhalf, float* __restrict__ rbias,
                             float* __restrict__ counts, unsigned int* __restrict__ arrive,
                             float* __restrict__ out, int Q, int R) {
    __shared__ short Bs[3][BN * DIM];          // 3 x 8KB ring
    __shared__ int s_done;

    const int tid  = threadIdx.x;
    const int lane = tid & 63;
    const int wave = tid >> 6;
    const int l31  = lane & 31;
    const int lhi  = lane >> 5;
    const int bid  = blockIdx.x;

    // ================= phase 0: prep disjoint slices =================
    const int QPB = Q / NBLK;                  // 8
    const int RPB = R / NBLK;                  // 32
    const float thr = *thr_p;
    for (int i = 0; i < (QPB + RPB + 3) / 4; ++i) {
        const int rl = wave + 4 * i;           // wave-uniform
        if (rl >= QPB + RPB) break;
        const bool isq = rl < QPB;
        const int row = isq ? bid * QPB + rl : bid * RPB + (rl - QPB);
        const float* src = (isq ? qe : re) + (size_t)row * DIM;
        __hip_bfloat16* dst = (isq ? qb : rb) + (size_t)row * DIM;
        float2 v = ((const float2*)src)[lane];
        float s = v.x * v.x + v.y * v.y;
        __hip_bfloat162 b;
        b.x = __float2bfloat16(v.x);
        b.y = __float2bfloat16(v.y);
        ((__hip_bfloat162*)dst)[lane] = b;
        #pragma unroll
        for (int off = 32; off > 0; off >>= 1) s += __shfl_down(s, off);
        if (lane == 0) {
            if (isq) qhalf[row] = 0.5f * s;
            else     rbias[row] = (thr >= 0.0f) ? 0.5f * s - 0.5f * thr * thr : 1e30f;
        }
    }
    if (tid < QPB) counts[bid * QPB + tid] = 0.0f;
    if (bid < (Q / BM) && tid == 0) arrive[bid] = 0u;

    cg::this_grid().sync();

    // ================= phase 1: MFMA distance-count =================
    const int tileM  = bid >> 6;
    const int segIdx = bid & (NSEG - 1);
    const int seg  = R / NSEG;                 // 256
    const int base = segIdx * seg;
    const int NT   = seg / BN;                 // 8
    const int qrow0 = tileM * BM + wave * 128;

    const char* qbc = (const char*)qb;
    const char* rbc = (const char*)rb;

    // stage one 32x128 bf16 tile (8KB): linear LDS dest, XOR-swizzle folded
    // into the GLOBAL source column (rule #21: both-sides-or-neither).
    auto stage = [&](int tt) {
        short* buf = Bs[tt % 3];
        #pragma unroll
        for (int j = 0; j < 2; ++j) {
            const int lds_byte = (wave * 2 + j) * 1024 + lane * 16;
            const int row = lds_byte >> 8;     // 0..31
            const int col = lds_byte & 255;
            const int src = (base + tt * BN + row) * ROWB + (col ^ ((row & 15) << 4));
            __builtin_amdgcn_global_load_lds(
                (const __attribute__((address_space(1))) unsigned int*)(rbc + src),
                (__attribute__((address_space(3))) unsigned int*)((char*)buf + lds_byte),
                16, 0, 0);
        }
    };

    // A fragments: 128 query rows x K=128 (32x32x16 layout: row=l31, k=lhi*8+j)
    short8 a[8][4];                            // 128 VGPR
    #pragma unroll
    for (int ks = 0; ks < 8; ++ks)
        #pragma unroll
        for (int mi = 0; mi < 4; ++mi)
            a[ks][mi] = *(const short8*)(qbc + (size_t)(qrow0 + mi * 32 + l31) * ROWB
                                         + ks * 32 + lhi * 16);

    // wave-level min of the 128 query half-norms (conservative screen bound)
    float minqh;
    {
        float mq = fminf(qhalf[qrow0 + lane], qhalf[qrow0 + 64 + lane]);
        #pragma unroll
        for (int off = 32; off > 0; off >>= 1) mq = fminf(mq, __shfl_xor(mq, off));
        minqh = mq;
    }

    stage(0);
    if (NT > 1) { stage(1); VMCNT(2); } else { VMCNT(0); }

    for (int t = 0; t < NT; ++t) {
        __builtin_amdgcn_s_barrier();          // all waves' tile-t loads confirmed
        __builtin_amdgcn_sched_barrier(0);
        if (t + 2 < NT) stage(t + 2);          // slot (t+2)%3 free since round t-1

        const char* cur = (const char*)Bs[t % 3];
        f32x16 acc[4] = {};

        __builtin_amdgcn_s_setprio(1);
        #pragma unroll
        for (int ks = 0; ks < 8; ++ks) {
            const int cb = (ks * 32 + lhi * 16) ^ ((l31 & 15) << 4);
            const short8 b = *(const short8*)(cur + l31 * ROWB + cb);
            #pragma unroll
            for (int mi = 0; mi < 4; ++mi)
                acc[mi] = __builtin_amdgcn_mfma_f32_32x32x16_bf16(a[ks][mi], b, acc[mi], 0, 0, 0);
        }
        __builtin_amdgcn_s_setprio(0);

        // ---- screened epilogue (per-lane rbias bound) ----
        const float rbv = rbias[base + t * BN + l31];
        f32x16 m01 = acc[0], m23 = acc[2];
        #pragma unroll
        for (int r = 0; r < 16; ++r) {
            m01[r] = fmaxf(m01[r], acc[1][r]);
            m23[r] = fmaxf(m23[r], acc[3][r]);
        }
        float mx = fmaxf(m01[0], m23[0]);
        #pragma unroll
        for (int r = 1; r < 16; ++r) mx = fmaxf(mx, fmaxf(m01[r], m23[r]));

        if (__any(mx >= minqh + rbv)) {        // rare slow path (generic-correct)
            #pragma unroll
            for (int mi = 0; mi < 4; ++mi)
                #pragma unroll
                for (int reg = 0; reg < 16; ++reg) {
                    // 32x32 C layout: row = (reg&3) + 8*(reg>>2) + 4*lhi
                    const int row = qrow0 + mi * 32 + (reg & 3) + 8 * (reg >> 2) + 4 * lhi;
                    float cnt = (acc[mi][reg] >= qhalf[row] + rbv) ? 1.0f : 0.0f;
                    cnt += __shfl_xor(cnt, 1);
                    cnt += __shfl_xor(cnt, 2);
                    cnt += __shfl_xor(cnt, 4);
                    cnt += __shfl_xor(cnt, 8);
                    cnt += __shfl_xor(cnt, 16);
                    if (l31 == 0 && cnt != 0.0f)
                        atomicAdd(&counts[row], cnt);
                }
        }

        if (t + 2 < NT) { VMCNT(2); }          // tile t+1 resident; t+2 in flight
        else            { VMCNT(0); }
    }

    // ================= phase 2: arrival-counter finalize =================
    __threadfence();                           // release my counts atomics
    __syncthreads();                           // whole block's fences done
    if (tid == 0) {
        unsigned int old = atomicAdd(&arrive[tileM], 1u);
        s_done = (old == (unsigned)(NSEG - 1));
    }
    __syncthreads();
    if (s_done) {                              // last seg-block for this tileM
        __threadfence();                       // acquire all blocks' counts
        const float k = (R < 100) ? (float)R : 100.0f;
        for (int i = tid; i < BM; i += 256) {
            const int row = tileM * BM + i;
            out[row] = fminf(counts[row], k) / k;
        }
    }
}

extern "C" void kernel_launch(void* const* d_in, const int* in_sizes, int n_in,
                              void* d_out, int out_size, void* d_ws, size_t ws_size,
                              hipStream_t stream) {
    const float* qe  = (const float*)d_in[0];
    const float* re  = (const float*)d_in[1];
    const float* thr = (const float*)d_in[2];
    float* out = (float*)d_out;

    int Q = in_sizes[0] / DIM;   // 4096
    int R = in_sizes[1] / DIM;   // 16384

    char* ws = (char*)d_ws;
    __hip_bfloat16* qb = (__hip_bfloat16*)ws;
    __hip_bfloat16* rb = (__hip_bfloat16*)(ws + (size_t)Q * DIM * 2);
    float* qhalf  = (float*)(ws + (size_t)(Q + R) * DIM * 2);
    float* rbias  = qhalf + Q;
    float* counts = rbias + R;
    unsigned int* arrive = (unsigned int*)(counts + Q);   // Q/BM entries

    void* args[] = { (void*)&qe, (void*)&re, (void*)&thr, (void*)&qb, (void*)&rb,
                     (void*)&qhalf, (void*)&rbias, (void*)&counts, (void*)&arrive,
                     (void*)&out, (void*)&Q, (void*)&R };
    hipLaunchCooperativeKernel((void*)fused_kernel, dim3(NBLK), dim3(256),
                               args, 0, stream);
}

// Round 8
// 61.515 us; speedup vs baseline: 2.0774x; 2.0774x over previous
//
#include <hip/hip_runtime.h>
#include <hip/hip_bf16.h>

// out[q] = min(|{r : dist(q,r) <= thr}|, 100) / 100   (top-k unnecessary:
// any distance <= thr is among the 100 smallest unless count > 100, which clamps)
//
// Q=4096, R=16384, D=128. hit <=> dot(q,r) >= 0.5|q|^2 + (0.5|r|^2 - 0.5 thr^2)
// Two kernels: prep (bf16 cast + folded norms + zero counts/arrive) and
// dist+finalize (32x32x16 MFMA, depth-3 LDS ring, counted vmcnt, 64 refs per
// barrier round; last-arriving segment block finalizes its 512 output rows).

#define DIM   128
#define ROWB  256              // bytes per bf16 row
#define BM    512              // queries per block (4 waves x 128)
#define BN    64               // refs per barrier round (2 x 32-ref halves)
#define NSEG  64               // segments along R (256 refs each)

typedef __attribute__((ext_vector_type(8)))  short short8;
typedef __attribute__((ext_vector_type(16))) float f32x16;

#define VMCNT(n) asm volatile("s_waitcnt vmcnt(" #n ")" ::: "memory")

// ---------------- prep: bf16 cast, folded norms/bias, zero counts ----------
__global__ void prep_kernel(const float* __restrict__ qe, const float* __restrict__ re,
                            __hip_bfloat16* __restrict__ qb, __hip_bfloat16* __restrict__ rb,
                            float* __restrict__ qhalf, float* __restrict__ rbias,
                            float* __restrict__ counts, unsigned int* __restrict__ arrive,
                            const float* __restrict__ thr_p, int Q, int R) {
    const int wave = threadIdx.x >> 6;
    const int lane = threadIdx.x & 63;
    const int row = blockIdx.x * 4 + wave;
    if (blockIdx.x == 0 && threadIdx.x < (unsigned)(Q / BM)) arrive[threadIdx.x] = 0u;
    if (row >= Q + R) return;
    const float* src;
    __hip_bfloat16* dst;
    if (row < Q) {
        src = qe + (size_t)row * DIM;
        dst = qb + (size_t)row * DIM;
        if (lane == 0) counts[row] = 0.0f;
    } else {
        src = re + (size_t)(row - Q) * DIM;
        dst = rb + (size_t)(row - Q) * DIM;
    }
    float2 v = ((const float2*)src)[lane];
    float s = v.x * v.x + v.y * v.y;
    __hip_bfloat162 b;
    b.x = __float2bfloat16(v.x);
    b.y = __float2bfloat16(v.y);
    ((__hip_bfloat162*)dst)[lane] = b;
    #pragma unroll
    for (int off = 32; off > 0; off >>= 1) s += __shfl_down(s, off);
    if (lane == 0) {
        if (row < Q) qhalf[row] = 0.5f * s;
        else {
            const float thr = *thr_p;
            rbias[row - Q] = (thr >= 0.0f) ? 0.5f * s - 0.5f * thr * thr : 1e30f;
        }
    }
}

// ---------------- main: 32x32x16 MFMA + fused finalize ---------------------
__launch_bounds__(256, 2)
__global__ void dist_count_kernel(const __hip_bfloat16* __restrict__ qb,
                                  const __hip_bfloat16* __restrict__ rb,
                                  const float* __restrict__ qhalf,
                                  const float* __restrict__ rbias,
                                  float* __restrict__ counts,
                                  unsigned int* __restrict__ arrive,
                                  float* __restrict__ out,
                                  int Q, int R) {
    __shared__ short Bs[3][BN * DIM];          // 3 x 16KB ring
    __shared__ int s_done;

    const int tid  = threadIdx.x;
    const int lane = tid & 63;
    const int wave = tid >> 6;
    const int l31  = lane & 31;
    const int lhi  = lane >> 5;

    const int seg  = R / NSEG;                 // 256
    const int base = blockIdx.x * seg;
    const int tileM = blockIdx.y;
    const int NT   = seg / BN;                 // 4
    const int qrow0 = tileM * BM + wave * 128;

    const char* qbc = (const char*)qb;
    const char* rbc = (const char*)rb;

    // stage one 64x128 bf16 tile (16KB): linear LDS dest, XOR-swizzle folded
    // into the GLOBAL source column (rule #21: both-sides-or-neither).
    auto stage = [&](int tt) {
        short* buf = Bs[tt % 3];
        #pragma unroll
        for (int j = 0; j < 4; ++j) {
            const int lds_byte = (wave * 4 + j) * 1024 + lane * 16;
            const int row = lds_byte >> 8;     // 0..63
            const int col = lds_byte & 255;
            const int src = (base + tt * BN + row) * ROWB + (col ^ ((row & 15) << 4));
            __builtin_amdgcn_global_load_lds(
                (const __attribute__((address_space(1))) unsigned int*)(rbc + src),
                (__attribute__((address_space(3))) unsigned int*)((char*)buf + lds_byte),
                16, 0, 0);
        }
    };

    // A fragments: 128 query rows x K=128 (32x32x16 layout: row=l31, k=lhi*8+j)
    short8 a[8][4];                            // 128 VGPR
    #pragma unroll
    for (int ks = 0; ks < 8; ++ks)
        #pragma unroll
        for (int mi = 0; mi < 4; ++mi)
            a[ks][mi] = *(const short8*)(qbc + (size_t)(qrow0 + mi * 32 + l31) * ROWB
                                         + ks * 32 + lhi * 16);

    // wave-level min of the 128 query half-norms (conservative screen bound)
    float minqh;
    {
        float mq = fminf(qhalf[qrow0 + lane], qhalf[qrow0 + 64 + lane]);
        #pragma unroll
        for (int off = 32; off > 0; off >>= 1) mq = fminf(mq, __shfl_xor(mq, off));
        minqh = mq;
    }

    // preload per-half rbias for all rounds (8 halves)
    float rbv[8];
    #pragma unroll
    for (int i = 0; i < 8; ++i) rbv[i] = rbias[base + i * 32 + l31];

    stage(0);
    stage(1);
    VMCNT(4);                                  // tile 0's loads (mine) done

    for (int t = 0; t < NT; ++t) {
        __builtin_amdgcn_s_barrier();          // all waves' tile-t loads confirmed
        __builtin_amdgcn_sched_barrier(0);
        if (t + 2 < NT) stage(t + 2);          // slot (t+2)%3 free since round t-1

        const char* cur = (const char*)Bs[t % 3];

        #pragma unroll
        for (int h = 0; h < 2; ++h) {          // two 32-ref halves per round
            f32x16 acc[4] = {};
            __builtin_amdgcn_s_setprio(1);
            #pragma unroll
            for (int ks = 0; ks < 8; ++ks) {
                const int cb = (ks * 32 + lhi * 16) ^ ((l31 & 15) << 4);
                const short8 b = *(const short8*)(cur + (h * 32 + l31) * ROWB + cb);
                #pragma unroll
                for (int mi = 0; mi < 4; ++mi)
                    acc[mi] = __builtin_amdgcn_mfma_f32_32x32x16_bf16(a[ks][mi], b, acc[mi], 0, 0, 0);
            }
            __builtin_amdgcn_s_setprio(0);

            // ---- screened epilogue (v_max3-friendly tree) ----
            const float rb_h = rbv[t * 2 + h];
            f32x16 m01 = acc[0], m23 = acc[2];
            #pragma unroll
            for (int r = 0; r < 16; ++r) {
                m01[r] = fmaxf(m01[r], acc[1][r]);
                m23[r] = fmaxf(m23[r], acc[3][r]);
            }
            float mx = fmaxf(fmaxf(m01[0], m23[0]), fmaxf(m01[1], m23[1]));
            #pragma unroll
            for (int r = 2; r < 16; r += 2)
                mx = fmaxf(mx, fmaxf(fmaxf(m01[r], m23[r]), fmaxf(m01[r + 1], m23[r + 1])));

            if (__any(mx >= minqh + rb_h)) {   // rare slow path (generic-correct)
                #pragma unroll
                for (int mi = 0; mi < 4; ++mi)
                    #pragma unroll
                    for (int reg = 0; reg < 16; ++reg) {
                        // 32x32 C layout: row = (reg&3) + 8*(reg>>2) + 4*lhi
                        const int row = qrow0 + mi * 32 + (reg & 3) + 8 * (reg >> 2) + 4 * lhi;
                        float cnt = (acc[mi][reg] >= qhalf[row] + rb_h) ? 1.0f : 0.0f;
                        cnt += __shfl_xor(cnt, 1);
                        cnt += __shfl_xor(cnt, 2);
                        cnt += __shfl_xor(cnt, 4);
                        cnt += __shfl_xor(cnt, 8);
                        cnt += __shfl_xor(cnt, 16);
                        if (l31 == 0 && cnt != 0.0f)
                            atomicAdd(&counts[row], cnt);
                    }
            }
        }

        if (t + 2 < NT) { VMCNT(4); }          // tile t+1 resident; t+2 in flight
        else            { VMCNT(0); }
    }

    // ---- fused finalize: last-arriving segment block writes this tileM ----
    __threadfence();                           // release my counts atomics
    __syncthreads();                           // whole block's fences done
    if (tid == 0) {
        unsigned int old = atomicAdd(&arrive[tileM], 1u);
        s_done = (old == (unsigned)(NSEG - 1));
    }
    __syncthreads();
    if (s_done) {                              // runs after all blocks' releases
        __threadfence();
        const float k = (R < 100) ? (float)R : 100.0f;
        for (int i = tid; i < BM; i += 256) {
            const int row = tileM * BM + i;
            out[row] = fminf(counts[row], k) / k;
        }
    }
}

extern "C" void kernel_launch(void* const* d_in, const int* in_sizes, int n_in,
                              void* d_out, int out_size, void* d_ws, size_t ws_size,
                              hipStream_t stream) {
    const float* qe  = (const float*)d_in[0];
    const float* re  = (const float*)d_in[1];
    const float* thr = (const float*)d_in[2];
    float* out = (float*)d_out;

    const int Q = in_sizes[0] / DIM;   // 4096
    const int R = in_sizes[1] / DIM;   // 16384

    char* ws = (char*)d_ws;
    __hip_bfloat16* qb = (__hip_bfloat16*)ws;
    __hip_bfloat16* rb = (__hip_bfloat16*)(ws + (size_t)Q * DIM * 2);
    float* qhalf  = (float*)(ws + (size_t)(Q + R) * DIM * 2);
    float* rbias  = qhalf + Q;
    float* counts = rbias + R;
    unsigned int* arrive = (unsigned int*)(counts + Q);   // Q/BM entries

    const int rows = Q + R;
    prep_kernel<<<(rows + 3) / 4, 256, 0, stream>>>(qe, re, qb, rb, qhalf, rbias,
                                                    counts, arrive, thr, Q, R);

    dim3 grid(NSEG, Q / BM);           // (64, 8) = 512 blocks = 2/CU
    dist_count_kernel<<<grid, 256, 0, stream>>>(qb, rb, qhalf, rbias, counts,
                                                arrive, out, Q, R);
}